// Round 1
// baseline (188.912 us; speedup 1.0000x reference)
//
#include <hip/hip_runtime.h>
#include <math.h>

// CRF loss: B=256, L=256, T=50.
// One block (256 threads = 4 waves) per batch element.
// lane (0..63) = "to" tag (>=50 padded); wave g = from-group rows [13g, 13g+12].
// Log2-domain forward scan with running renormalization:
//   stored A_l = alpha_l - S_l,  S_{l+1} = S_l + c_l,  c_l = max_f A_l[f] (exact, same-step via LDS)
//   A_{l+1}[to] = log2( sum_f exp2(A_l[f] + trans[f][to]/ln2) ) + emit_{l+1}[to]/ln2 - c_l

#define TAGS 50
#define LEN 256
#define INV_LN2 1.4426950408889634f
#define LN2 0.6931471805599453f

#if __has_builtin(__builtin_amdgcn_exp2f)
#define EXP2F(x) __builtin_amdgcn_exp2f(x)
#else
#define EXP2F(x) exp2f(x)
#endif
#if __has_builtin(__builtin_amdgcn_logf)
#define LOG2F(x) __builtin_amdgcn_logf(x)
#else
#define LOG2F(x) log2f(x)
#endif

__global__ __launch_bounds__(256) void crf_fwd_kernel(
    const float* __restrict__ feats,   // (B, L, T)
    const float* __restrict__ trans,   // (T, T)
    const int*   __restrict__ tags,    // (B, L)
    const int*   __restrict__ mask,    // (B, L)
    float*       __restrict__ out)     // (B,)
{
  const int b    = blockIdx.x;
  const int t    = threadIdx.x;
  const int g    = t >> 6;            // wave id 0..3 = from-group
  const int lane = t & 63;            // = "to" tag (lanes >= 50 are pad)
  const int toc  = lane < TAGS ? lane : (TAGS - 1);
  const int goff = g * 13;            // group rows goff..goff+12 (g=3 covers 39..51, rows 50/51 are -inf pad)

  __shared__ float alpha[64];         // A values; [50..63] = -inf pad, never rewritten
  __shared__ float partial[4 * 64];   // per-group partial sums, [g*64 + to]
  __shared__ float maxpart[4];        // per-group max of A
  __shared__ float red[8];            // gold-score reduction

  const float* fb = feats + (size_t)b * (LEN * TAGS);
  const int*   tb = tags + b * LEN;
  const int*   mb = mask + b * LEN;

  // Preload this thread's trans column slice (log2-scaled) into registers.
  float t2col[13];
#pragma unroll
  for (int f = 0; f < 13; ++f) {
    int row = goff + f;
    if (row > TAGS - 1) row = TAGS - 1;   // pad rows: clamp load (contribution killed by -inf alpha)
    t2col[f] = trans[row * TAGS + toc] * INV_LN2;
  }

  // Init A_0 = emit_0 / ln2 (S_0 = 0); pad lanes -> -inf.
  if (t < TAGS)      alpha[t] = fb[t] * INV_LN2;
  else if (t < 64)   alpha[t] = -INFINITY;
  __syncthreads();

  float S = 0.0f;
  // Software-pipelined prefetch of emit/mask for step l=1.
  float e_next = fb[1 * TAGS + toc];
  int   m_next = mb[1];

  for (int l = 1; l < LEN; ++l) {
    const float e_cur = e_next;
    const int   m_cur = m_next;
    if (l + 1 < LEN) {                 // prefetch next step (hides global latency across the step)
      e_next = fb[(l + 1) * TAGS + toc];
      m_next = mb[l + 1];
    }

    // ---- Phase A: partial logsumexp over this wave's from-group ----
    const float aprev = alpha[toc];    // needed only for mask path
    float loc = -INFINITY;
    float s0 = 0.0f, s1 = 0.0f;        // 2 accumulators to break the exp->add chain
#pragma unroll
    for (int f = 0; f < 13; ++f) {
      const float a = alpha[goff + f];   // LDS broadcast read (wave-uniform addr)
      loc = fmaxf(loc, a);
      const float v = EXP2F(a + t2col[f]);
      if (f & 1) s1 += v; else s0 += v;
    }
    partial[g * 64 + lane] = s0 + s1;  // consecutive lanes -> conflict-free
    if (lane == 0) maxpart[g] = loc;
    __syncthreads();

    // ---- Finalize (redundant across all 4 waves; only wave 0 writes) ----
    const float p = partial[0 * 64 + lane] + partial[1 * 64 + lane]
                  + partial[2 * 64 + lane] + partial[3 * 64 + lane];
    const float c = fmaxf(fmaxf(maxpart[0], maxpart[1]),
                          fmaxf(maxpart[2], maxpart[3]));   // exact max of A_{l-1}
    float newA = LOG2F(p) + e_cur * INV_LN2 - c;
    if (m_cur <= 0) newA = aprev - c;  // masked step: alpha unchanged (absolute), shifted by c in stored domain
    if (g == 0 && lane < TAGS) alpha[lane] = newA;
    S += c;
    __syncthreads();
  }

  // ---- Gold score: thread t handles sequence position l = t ----
  const int tg = tb[t];
  const int mm = mb[t];
  float gp = 0.0f;
  if (mm > 0) {
    gp = fb[t * TAGS + tg];                       // emit_sc[l] * m[l]
    if (t >= 1) gp += trans[tb[t - 1] * TAGS + tg];  // trans_sc uses m[l] too
  }
#pragma unroll
  for (int off = 32; off; off >>= 1) gp += __shfl_xor(gp, off, 64);
  if (lane == 0) red[g] = gp;
  __syncthreads();
  if (t == 0) red[4] = red[0] + red[1] + red[2] + red[3];
  __syncthreads();

  // ---- Final logsumexp over A_{L-1} (wave 0 only) ----
  if (g == 0) {
    const float a = alpha[lane];       // pad lanes are -inf
    float m = a;
#pragma unroll
    for (int off = 32; off; off >>= 1) m = fmaxf(m, __shfl_xor(m, off, 64));
    float sum = EXP2F(a - m);          // -inf - finite = -inf -> exp2 -> 0
#pragma unroll
    for (int off = 32; off; off >>= 1) sum += __shfl_xor(sum, off, 64);
    if (lane == 0) {
      const float all_path = LN2 * (S + m + LOG2F(sum));
      out[b] = all_path - red[4];
    }
  }
}

extern "C" void kernel_launch(void* const* d_in, const int* in_sizes, int n_in,
                              void* d_out, int out_size, void* d_ws, size_t ws_size,
                              hipStream_t stream) {
  const float* feats = (const float*)d_in[0];  // (B, L, T) fp32
  const float* trans = (const float*)d_in[1];  // (T, T)    fp32
  const int*   tags  = (const int*)d_in[2];    // (B, L)    int32
  const int*   mask  = (const int*)d_in[3];    // (B, L)    int32
  float* out = (float*)d_out;                  // (B,)      fp32

  const int B = out_size;                      // 256
  crf_fwd_kernel<<<B, 256, 0, stream>>>(feats, trans, tags, mask, out);
}

// Round 2
// 170.269 us; speedup vs baseline: 1.1095x; 1.1095x over previous
//
#include <hip/hip_runtime.h>
#include <math.h>

// CRF loss: B=256, L=256, T=50. One block (256 thr = 4 waves) per batch element.
// lane = "to" tag (>=50 pad); wave g covers from-rows [16g, 16g+15] (rows >=50 dead via -inf alpha).
// Log2-domain scan, renormalized: stored A = alpha - S, S += c (c = exact max of prev A).
//
// Key change vs prev round: feats/mask preloaded to LDS (no global loads in the
// scan -> the compiler's s_waitcnt vmcnt(0) before s_barrier no longer puts a
// ~900-cycle cold HBM load on the critical path), and ONE barrier per step:
// alpha lives in a register (all waves compute phase B redundantly), staged
// through a per-wave private LDS copy (wave-synchronous), partial sums
// double-buffered by step parity.

#define TAGS 50
#define LEN 256
#define INV_LN2 1.4426950408889634f
#define LN2 0.6931471805599453f

#if __has_builtin(__builtin_amdgcn_exp2f)
#define EXP2F(x) __builtin_amdgcn_exp2f(x)
#else
#define EXP2F(x) exp2f(x)
#endif
#if __has_builtin(__builtin_amdgcn_logf)
#define LOG2F(x) __builtin_amdgcn_logf(x)
#else
#define LOG2F(x) log2f(x)
#endif

__global__ __launch_bounds__(256) void crf_fwd_kernel(
    const float* __restrict__ feats,   // (B, L, T)
    const float* __restrict__ trans,   // (T, T)
    const int*   __restrict__ tags,    // (B, L)
    const int*   __restrict__ mask,    // (B, L)
    float*       __restrict__ out)     // (B,)
{
  const int b    = blockIdx.x;
  const int t    = threadIdx.x;
  const int g    = t >> 6;            // wave id 0..3
  const int lane = t & 63;            // "to" tag (>=50 pad)
  const int toc  = lane < TAGS ? lane : (TAGS - 1);
  const int goff = g * 16;            // from-rows [goff, goff+15]

  __shared__ __align__(16) float feats_lds[LEN * TAGS]; // emits, prescaled by 1/ln2
  __shared__ int   mask_lds[LEN];
  __shared__ __align__(16) float alpha_priv[4][64];     // per-wave private stage
  __shared__ float partialDB[2][4][64];                 // parity-double-buffered
  __shared__ __align__(16) float maxDB[2][4];
  __shared__ float red[8];

  const float* fb = feats + (size_t)b * (LEN * TAGS);
  const int*   tb = tags + b * LEN;
  const int*   mb = mask + b * LEN;

  // ---- Bulk preload: feats[b] (12800 floats, prescaled) + mask[b] ----
  {
    const float4* fv = (const float4*)fb;               // 3200 float4, 16B-aligned
    for (int i = t; i < (LEN * TAGS) / 4; i += 256) {
      float4 v = fv[i];
      v.x *= INV_LN2; v.y *= INV_LN2; v.z *= INV_LN2; v.w *= INV_LN2;
      *(float4*)&feats_lds[i * 4] = v;
    }
    mask_lds[t] = mb[t];
  }

  // Trans column slice for this wave's 16 from-rows (log2-scaled).
  float t2col[16];
#pragma unroll
  for (int f = 0; f < 16; ++f) {
    int row = goff + f;
    if (row > TAGS - 1) row = TAGS - 1;  // dead rows (alpha=-inf) -> value irrelevant
    t2col[f] = trans[row * TAGS + toc] * INV_LN2;
  }

  __syncthreads();

  float A = (lane < TAGS) ? feats_lds[lane] : -INFINITY; // stored log2-alpha (prescaled emit_0)
  float S = 0.0f;

  for (int l = 1; l < LEN; ++l) {
    const int par = l & 1;

    // Stage own A for wave-internal broadcast (private copy: no cross-wave hazard).
    alpha_priv[g][lane] = A;
    const float e_cur = feats_lds[l * TAGS + toc];   // prescaled emit
    const int   m_cur = mask_lds[l];
    __builtin_amdgcn_wave_barrier();
    __builtin_amdgcn_s_waitcnt(0xC07F);              // lgkmcnt(0): write visible
    __builtin_amdgcn_wave_barrier();

    // ---- Phase A: partial logsumexp over this wave's 16 from-rows ----
    const float4 a0 = *(const float4*)&alpha_priv[g][goff + 0];
    const float4 a1 = *(const float4*)&alpha_priv[g][goff + 4];
    const float4 a2 = *(const float4*)&alpha_priv[g][goff + 8];
    const float4 a3 = *(const float4*)&alpha_priv[g][goff + 12];
    const float av[16] = {a0.x, a0.y, a0.z, a0.w, a1.x, a1.y, a1.z, a1.w,
                          a2.x, a2.y, a2.z, a2.w, a3.x, a3.y, a3.z, a3.w};
    float loc = -INFINITY;
    float s0 = 0.0f, s1 = 0.0f;
#pragma unroll
    for (int f = 0; f < 16; ++f) {
      loc = fmaxf(loc, av[f]);
      const float v = EXP2F(av[f] + t2col[f]);       // exp2(-inf + x) = 0 for pads
      if (f & 1) s1 += v; else s0 += v;
    }
    partialDB[par][g][lane] = s0 + s1;
    if (lane == 0) maxDB[par][g] = loc;
    __syncthreads();                                  // the ONE barrier per step

    // ---- Phase B: finalize (all waves redundantly; alpha stays in registers) ----
    const float p = partialDB[par][0][lane] + partialDB[par][1][lane]
                  + partialDB[par][2][lane] + partialDB[par][3][lane];
    const float4 mx = *(const float4*)&maxDB[par][0];
    const float c = fmaxf(fmaxf(mx.x, mx.y), fmaxf(mx.z, mx.w)); // exact max of prev A
    float newA = LOG2F(p) + e_cur - c;
    newA = (m_cur > 0) ? newA : (A - c);              // masked: alpha unchanged (abs), shift stored
    if (lane >= TAGS) newA = -INFINITY;               // keep pads dead
    A = newA;
    S += c;
  }

  // ---- Gold score: thread t handles sequence position l = t ----
  const int tg = tb[t];
  const int mm = mb[t];
  float gp = 0.0f;
  if (mm > 0) {
    gp = fb[t * TAGS + tg];
    if (t >= 1) gp += trans[tb[t - 1] * TAGS + tg];
  }
#pragma unroll
  for (int off = 32; off; off >>= 1) gp += __shfl_xor(gp, off, 64);
  if (lane == 0) red[g] = gp;
  __syncthreads();
  if (t == 0) red[4] = red[0] + red[1] + red[2] + red[3];
  __syncthreads();

  // ---- Final logsumexp over A (wave 0; pads are -inf) ----
  if (g == 0) {
    float m = A;
#pragma unroll
    for (int off = 32; off; off >>= 1) m = fmaxf(m, __shfl_xor(m, off, 64));
    float sum = EXP2F(A - m);
#pragma unroll
    for (int off = 32; off; off >>= 1) sum += __shfl_xor(sum, off, 64);
    if (lane == 0) {
      const float all_path = LN2 * (S + m + LOG2F(sum));
      out[b] = all_path - red[4];
    }
  }
}

extern "C" void kernel_launch(void* const* d_in, const int* in_sizes, int n_in,
                              void* d_out, int out_size, void* d_ws, size_t ws_size,
                              hipStream_t stream) {
  const float* feats = (const float*)d_in[0];
  const float* trans = (const float*)d_in[1];
  const int*   tags  = (const int*)d_in[2];
  const int*   mask  = (const int*)d_in[3];
  float* out = (float*)d_out;

  const int B = out_size;  // 256
  crf_fwd_kernel<<<B, 256, 0, stream>>>(feats, trans, tags, mask, out);
}